// Round 3
// baseline (9803.535 us; speedup 1.0000x reference)
//
#include <hip/hip_runtime.h>

#define NB 8192
#define NH 512
#define NZ 128
#define NIN 128
#define NN 512
#define NRW 16
#define NG 2048   // 4*NH

__device__ __forceinline__ float sigm(float x) { return 1.0f / (1.0f + expf(-x)); }

// Fused: gates = A @ Wl + bl + extra[eidx[row]]; then LSTM pointwise update.
// Block: 64 batch rows x 64 h-cols x 4 gates. A = h_in [NB,NH], Wl = W_lstm+128 rows [NH,NG].
__global__ __launch_bounds__(256)
void gate_lstm(const float* __restrict__ A,
               const float* __restrict__ Wl,
               const float* __restrict__ bl,
               const float* __restrict__ extra, const int* __restrict__ eidx,
               float* __restrict__ c, float* __restrict__ hout)
{
    __shared__ float As[16][64];
    __shared__ float Bs[16][4][64];
    const int bm = blockIdx.y << 6;
    const int bn = blockIdx.x << 6;
    const int tid = threadIdx.x;
    const int tx = tid & 15, ty = tid >> 4;
    const int ar = tid >> 2, ac = (tid & 3) << 2;   // A stage: row, k-quad
    const int bk = tid >> 4, bc = (tid & 15) << 2;  // B stage: k-row, col-quad
    float acc[4][4][4] = {};                        // [gate][row i][col j]
    const float* Ap = A + (size_t)(bm + ar) * NH + ac;
    const float* Wp = Wl + (size_t)bk * NG + bn + bc;
    for (int kb = 0; kb < NH; kb += 16) {
        const float4 av = *(const float4*)(Ap + kb);
        float4 bv[4];
#pragma unroll
        for (int g = 0; g < 4; ++g)
            bv[g] = *(const float4*)(Wp + (size_t)kb * NG + g * NH);
        __syncthreads();
        As[ac + 0][ar] = av.x; As[ac + 1][ar] = av.y;
        As[ac + 2][ar] = av.z; As[ac + 3][ar] = av.w;
#pragma unroll
        for (int g = 0; g < 4; ++g)
            *(float4*)&Bs[bk][g][bc] = bv[g];
        __syncthreads();
#pragma unroll
        for (int kk = 0; kk < 16; ++kk) {
            float a[4], b[4][4];
            *(float4*)a = *(const float4*)&As[kk][ty << 2];
#pragma unroll
            for (int g = 0; g < 4; ++g)
                *(float4*)b[g] = *(const float4*)&Bs[kk][g][tx << 2];
#pragma unroll
            for (int g = 0; g < 4; ++g)
#pragma unroll
                for (int i = 0; i < 4; ++i)
#pragma unroll
                    for (int j = 0; j < 4; ++j)
                        acc[g][i][j] = fmaf(a[i], b[g][j], acc[g][i][j]);
        }
    }
    const int row0 = bm + (ty << 2);
    const int col0 = bn + (tx << 2);
    float bi[4][4];
#pragma unroll
    for (int g = 0; g < 4; ++g)
        *(float4*)bi[g] = *(const float4*)(bl + g * NH + col0);
#pragma unroll
    for (int i = 0; i < 4; ++i) {
        const int row = row0 + i;
        const int e = eidx ? eidx[row] : row;
        float ex[4][4];
#pragma unroll
        for (int g = 0; g < 4; ++g)
            *(float4*)ex[g] = *(const float4*)(extra + (size_t)e * NG + g * NH + col0);
        float* cp = c + (size_t)row * NH + col0;
        const float4 c4 = *(const float4*)cp;
        const float cxa[4] = {c4.x, c4.y, c4.z, c4.w};
        float cy[4], hy[4];
#pragma unroll
        for (int j = 0; j < 4; ++j) {
            const float ig = acc[0][i][j] + bi[0][j] + ex[0][j];
            const float gg = acc[1][i][j] + bi[1][j] + ex[1][j];
            const float fg = acc[2][i][j] + bi[2][j] + ex[2][j];
            const float og = acc[3][i][j] + bi[3][j] + ex[3][j];
            const float cc = cxa[j] * sigm(fg + 1.0f) + sigm(ig) * tanhf(gg);
            cy[j] = cc;
            hy[j] = sigm(og) * tanhf(cc);
        }
        *(float4*)cp = make_float4(cy[0], cy[1], cy[2], cy[3]);
        *(float4*)(hout + (size_t)row * NH + col0) = make_float4(hy[0], hy[1], hy[2], hy[3]);
    }
}

// Generic C = act(A[M,K] @ W[K,N] + bias), 128x128 tile, 8x8 per thread (split 4+4 @64).
template<int ACT>
__global__ __launch_bounds__(256)
void gemm128(const float* __restrict__ A, int lda,
             const float* __restrict__ W, int ldw,
             const float* __restrict__ bias,
             float* __restrict__ C, int ldc, int K)
{
    __shared__ float As[16][128];
    __shared__ float Bs[16][128];
    const int bm = blockIdx.y << 7, bn = blockIdx.x << 7;
    const int tid = threadIdx.x;
    const int tx = tid & 15, ty = tid >> 4;
    const int sar = tid >> 1, sac = (tid & 1) << 3;   // A stage: row, k-offset
    const int sbk = tid >> 4, sbc = (tid & 15) << 3;  // B stage: k-row, col
    float acc[2][2][4][4] = {};
    const float* Ap = A + (size_t)(bm + sar) * lda + sac;
    const float* Wp = W + (size_t)sbk * ldw + bn + sbc;
    for (int kb = 0; kb < K; kb += 16) {
        const float4 av0 = *(const float4*)(Ap + kb);
        const float4 av1 = *(const float4*)(Ap + kb + 4);
        const float4 bv0 = *(const float4*)(Wp + (size_t)kb * ldw);
        const float4 bv1 = *(const float4*)(Wp + (size_t)kb * ldw + 4);
        __syncthreads();
        As[sac + 0][sar] = av0.x; As[sac + 1][sar] = av0.y;
        As[sac + 2][sar] = av0.z; As[sac + 3][sar] = av0.w;
        As[sac + 4][sar] = av1.x; As[sac + 5][sar] = av1.y;
        As[sac + 6][sar] = av1.z; As[sac + 7][sar] = av1.w;
        *(float4*)&Bs[sbk][sbc] = bv0;
        *(float4*)&Bs[sbk][sbc + 4] = bv1;
        __syncthreads();
#pragma unroll
        for (int kk = 0; kk < 16; ++kk) {
            float a[2][4], b[2][4];
            *(float4*)a[0] = *(const float4*)&As[kk][ty << 2];
            *(float4*)a[1] = *(const float4*)&As[kk][64 + (ty << 2)];
            *(float4*)b[0] = *(const float4*)&Bs[kk][tx << 2];
            *(float4*)b[1] = *(const float4*)&Bs[kk][64 + (tx << 2)];
#pragma unroll
            for (int rh = 0; rh < 2; ++rh)
#pragma unroll
                for (int ch = 0; ch < 2; ++ch)
#pragma unroll
                    for (int i = 0; i < 4; ++i)
#pragma unroll
                        for (int j = 0; j < 4; ++j)
                            acc[rh][ch][i][j] = fmaf(a[rh][i], b[ch][j], acc[rh][ch][i][j]);
        }
    }
    float4 bi4[2] = {make_float4(0.f,0.f,0.f,0.f), make_float4(0.f,0.f,0.f,0.f)};
    if (bias) {
        bi4[0] = *(const float4*)(bias + bn + (tx << 2));
        bi4[1] = *(const float4*)(bias + bn + 64 + (tx << 2));
    }
#pragma unroll
    for (int rh = 0; rh < 2; ++rh)
#pragma unroll
        for (int i = 0; i < 4; ++i) {
            const int row = bm + rh * 64 + (ty << 2) + i;
#pragma unroll
            for (int ch = 0; ch < 2; ++ch) {
                const int col = bn + ch * 64 + (tx << 2);
                float v0 = acc[rh][ch][i][0] + bi4[ch].x;
                float v1 = acc[rh][ch][i][1] + bi4[ch].y;
                float v2 = acc[rh][ch][i][2] + bi4[ch].z;
                float v3 = acc[rh][ch][i][3] + bi4[ch].w;
                if (ACT == 1) { v0 = tanhf(v0); v1 = tanhf(v1); v2 = tanhf(v2); v3 = tanhf(v3); }
                *(float4*)(C + (size_t)row * ldc + col) = make_float4(v0, v1, v2, v3);
            }
        }
}

// Per row b: argmax_j( logits[b,j] + gumbel(u[t,b,j]) ); one-hot f32 row + index.
__global__ __launch_bounds__(256)
void argmax_onehot(const float* __restrict__ logits, const float* __restrict__ gu,
                   float* __restrict__ out0, int* __restrict__ kidx, int t)
{
    const int b = blockIdx.x;
    const int tid = threadIdx.x;
    const float* lrow = logits + (size_t)b * NN;
    const float* urow = gu + ((size_t)t * NB + b) * NN;
    float best = -INFINITY;
    int bi = 0x7fffffff;
#pragma unroll
    for (int q = 0; q < 2; ++q) {
        const int j = tid + q * 256;
        const float u = urow[j];
        const float g = -logf(-logf(u + 1e-20f) + 1e-20f);
        const float v = lrow[j] + g;
        if (v > best || (v == best && j < bi)) { best = v; bi = j; }
    }
#pragma unroll
    for (int off = 32; off > 0; off >>= 1) {
        const float ov = __shfl_down(best, off);
        const int oi = __shfl_down(bi, off);
        if (ov > best || (ov == best && oi < bi)) { best = ov; bi = oi; }
    }
    __shared__ float sv[4];
    __shared__ int si[4];
    const int lane = tid & 63, w = tid >> 6;
    if (lane == 0) { sv[w] = best; si[w] = bi; }
    __syncthreads();
    if (tid == 0) {
        for (int q = 1; q < 4; ++q)
            if (sv[q] > best || (sv[q] == best && si[q] < bi)) { best = sv[q]; bi = si[q]; }
        si[0] = bi;
        kidx[(size_t)t * NB + b] = bi;
    }
    __syncthreads();
    const int win = si[0];
    float* orow = out0 + ((size_t)b * NRW + t) * NN;
#pragma unroll
    for (int q = 0; q < 2; ++q) {
        const int j = tid + q * 256;
        orow[j] = (j == win) ? 1.0f : 0.0f;
    }
}

// out1[b*RW + t] = dot(h[b,:], W_outl) + b_outl, one wave per row.
__global__ __launch_bounds__(256)
void rowdot(const float* __restrict__ h, const float* __restrict__ Woutl,
            const float* __restrict__ boutl, float* __restrict__ out1, int t)
{
    const int w = threadIdx.x >> 6;
    const int lane = threadIdx.x & 63;
    const int b = blockIdx.x * 4 + w;
    const float* hr = h + (size_t)b * NH;
    float s = 0.f;
#pragma unroll
    for (int q = 0; q < 8; ++q) s = fmaf(hr[lane + q * 64], Woutl[lane + q * 64], s);
#pragma unroll
    for (int off = 32; off > 0; off >>= 1) s += __shfl_down(s, off);
    if (lane == 0) out1[(size_t)b * NRW + t] = s + boutl[0];
}

extern "C" void kernel_launch(void* const* d_in, const int* in_sizes, int n_in,
                              void* d_out, int out_size, void* d_ws, size_t ws_size,
                              hipStream_t stream)
{
    const float* latent  = (const float*)d_in[0];
    const float* inputs  = (const float*)d_in[1];
    const float* gu      = (const float*)d_in[2];
    const float* W_int   = (const float*)d_in[3];
    const float* b_int   = (const float*)d_in[4];
    const float* W_intl  = (const float*)d_in[5];
    const float* b_intl  = (const float*)d_in[6];
    const float* W_hup   = (const float*)d_in[7];
    const float* b_hup   = (const float*)d_in[8];
    const float* W_cup   = (const float*)d_in[9];
    const float* b_cup   = (const float*)d_in[10];
    const float* W_hupl  = (const float*)d_in[11];
    const float* b_hupl  = (const float*)d_in[12];
    const float* W_cupl  = (const float*)d_in[13];
    const float* b_cupl  = (const float*)d_in[14];
    const float* W_lstm  = (const float*)d_in[15];
    const float* b_lstm  = (const float*)d_in[16];
    const float* W_up    = (const float*)d_in[17];
    const float* b_up    = (const float*)d_in[18];
    const float* W_down  = (const float*)d_in[19];
    const float* W_downl = (const float*)d_in[20];
    const float* W_outl  = (const float*)d_in[21];
    const float* b_outl  = (const float*)d_in[22];

    float* out0 = (float*)d_out;                 // [B, RW, N]
    float* out1 = out0 + (size_t)NB * NRW * NN;  // [B, RW, 1]

    float* ws     = (float*)d_ws;
    float* h0     = ws;                          // NB*NH
    float* h1     = h0 + (size_t)NB * NH;        // NB*NH
    float* c      = h1 + (size_t)NB * NH;        // NB*NH
    float* logits = c + (size_t)NB * NH;         // NB*NN (also 'inter' for inits)
    float* x0g    = logits + (size_t)NB * NN;    // NB*NG
    float* gdown  = x0g + (size_t)NB * NG;       // NN*NG
    float* gdownl = gdown + (size_t)NN * NG;     // NN*NG
    int*   kidx   = (int*)(gdownl + (size_t)NN * NG); // NRW*NB

    const dim3 blk(256);
    const dim3 g_gate(NH / 64, NB / 64);          // 8 x 128
    const dim3 g_log(NN / 128, NB / 128);         // 4 x 64
    const dim3 g_pre(NG / 128, NN / 128);         // 16 x 4
    const dim3 g_x0(NG / 128, NB / 128);          // 16 x 64
    const float* Wl = W_lstm + (size_t)NIN * NG;

    // Precompute gathers: G_down = W_down @ W_lstm[:128], G_downl likewise,
    // x0g = inputs @ W_lstm[:128] (t=0 x-contribution).
    gemm128<0><<<g_pre, blk, 0, stream>>>(W_down, NIN, W_lstm, NG, nullptr, gdown, NG, NIN);
    gemm128<0><<<g_pre, blk, 0, stream>>>(W_downl, NIN, W_lstm, NG, nullptr, gdownl, NG, NIN);
    gemm128<0><<<g_x0, blk, 0, stream>>>(inputs, NIN, W_lstm, NG, nullptr, x0g, NG, NIN);

    // ---- Loop 1 init: inter (in logits buf), h0, c ----
    gemm128<1><<<g_log, blk, 0, stream>>>(latent, NZ, W_int, NH, b_int, logits, NH, NZ);
    gemm128<1><<<g_log, blk, 0, stream>>>(logits, NH, W_hup, NH, b_hup, h0, NH, NH);
    gemm128<1><<<g_log, blk, 0, stream>>>(logits, NH, W_cup, NH, b_cup, c, NH, NH);

    float* hc = h0;
    float* hn = h1;
    for (int t = 0; t < NRW; ++t) {
        gate_lstm<<<g_gate, blk, 0, stream>>>(hc, Wl, b_lstm,
                                              t == 0 ? x0g : gdown,
                                              t == 0 ? nullptr : kidx + (size_t)(t - 1) * NB,
                                              c, hn);
        gemm128<0><<<g_log, blk, 0, stream>>>(hn, NH, W_up, NH, b_up, logits, NN, NH);
        argmax_onehot<<<dim3(NB), blk, 0, stream>>>(logits, gu, out0, kidx, t);
        float* tmp = hc; hc = hn; hn = tmp;
    }

    // ---- Loop 2 init ----
    gemm128<1><<<g_log, blk, 0, stream>>>(latent, NZ, W_intl, NH, b_intl, logits, NH, NZ);
    gemm128<1><<<g_log, blk, 0, stream>>>(logits, NH, W_hupl, NH, b_hupl, h0, NH, NH);
    gemm128<1><<<g_log, blk, 0, stream>>>(logits, NH, W_cupl, NH, b_cupl, c, NH, NH);

    hc = h0;
    hn = h1;
    for (int t = 0; t < NRW; ++t) {
        gate_lstm<<<g_gate, blk, 0, stream>>>(hc, Wl, b_lstm,
                                              gdownl, kidx + (size_t)t * NB, c, hn);
        rowdot<<<dim3(NB / 4), blk, 0, stream>>>(hn, W_outl, b_outl, out1, t);
        float* tmp = hc; hc = hn; hn = tmp;
    }
}